// Round 1
// baseline (2421.851 us; speedup 1.0000x reference)
//
#include <hip/hip_runtime.h>
#include <cstddef>

#define BB 16
#define CC_ 64
#define HH 192
#define WW 192
#define H2 64
#define W2 64
#define HW2 4096

// ---------------- Kernel 1: qk = conv3x3 stride3 (VALID) ----------------
// grid (B*H2, 8), block 256. Each block: one (b,py) row, 16 output channels.
// Threads: px = tid&63, cg = tid>>6 -> 4 co per thread.
__global__ __launch_bounds__(256) void k_qkconv(const float* __restrict__ x,
                                                const float* __restrict__ wqk,
                                                float* __restrict__ qk) {
  const int bx = blockIdx.x;
  const int b = bx >> 6, py = bx & 63;
  const int co_base = blockIdx.y * 16;
  const int tid = threadIdx.x;
  const int px = tid & 63, cg = tid >> 6;

  // w tile [cc][ci][12] (9 used, pad to 12 -> 16B-aligned float4 reads)
  __shared__ float wl[16 * 768];
  for (int e = tid; e < 16 * 576; e += 256) {
    int cc = e / 576, j = e % 576;
    int ci = j / 9, r9 = j % 9;
    wl[cc * 768 + ci * 12 + r9] = wqk[(size_t)co_base * 576 + e];
  }
  __syncthreads();

  float acc[4] = {0.f, 0.f, 0.f, 0.f};
  const float* xb = x + (size_t)b * CC_ * HH * WW + (3 * py) * WW + 3 * px;
  for (int ci = 0; ci < CC_; ++ci) {
    const float* xp = xb + (size_t)ci * (HH * WW);
    float p[9];
#pragma unroll
    for (int r = 0; r < 3; ++r)
#pragma unroll
      for (int s = 0; s < 3; ++s) p[r * 3 + s] = xp[r * WW + s];
#pragma unroll
    for (int c = 0; c < 4; ++c) {
      const float* w9 = &wl[(cg * 4 + c) * 768 + ci * 12];
      float4 wa = *(const float4*)(w9);
      float4 wb = *(const float4*)(w9 + 4);
      float w8 = w9[8];
      acc[c] += p[0] * wa.x + p[1] * wa.y + p[2] * wa.z + p[3] * wa.w +
                p[4] * wb.x + p[5] * wb.y + p[6] * wb.z + p[7] * wb.w +
                p[8] * w8;
    }
  }
  size_t ob = ((size_t)(b * 128 + co_base + cg * 4) * HW2) + py * 64 + px;
#pragma unroll
  for (int c = 0; c < 4; ++c) qk[ob + (size_t)c * HW2] = acc[c];
}

// ---------------- Kernel 2: attn[b,sh,co,ci] = <k[b,co], q_shift[b,ci]> ----
// grid B*25*4 (4-way hw split, atomicAdd into zeroed attn), block 256.
// 64x64 output tile per (b,shift); K-chunks of 32 hw staged in LDS (pad 36).
__global__ __launch_bounds__(256) void k_attn(const float* __restrict__ qk,
                                              float* __restrict__ attn) {
  int blk = blockIdx.x;
  int split = blk & 3;
  int tmp = blk >> 2;
  int sh = tmp % 25;
  int b = tmp / 25;
  int di = sh / 5, dj = sh % 5;
  const float* qb = qk + (size_t)(b * 128) * HW2;
  const float* kb = qb + (size_t)64 * HW2;
  __shared__ float kt[64 * 36];
  __shared__ float qt[64 * 36];
  int tid = threadIdx.x;
  int ty = tid >> 4, tx = tid & 15;
  float acc[4][4];
#pragma unroll
  for (int i = 0; i < 4; ++i)
#pragma unroll
    for (int j = 0; j < 4; ++j) acc[i][j] = 0.f;

  for (int chunk = 0; chunk < 32; ++chunk) {
    int hwb = split * 1024 + chunk * 32;
    int h = hwb >> 6, w0 = hwb & 63;  // chunk never crosses a row (32 | 64)
    // k tile: 512 float4 loads
#pragma unroll
    for (int i = 0; i < 2; ++i) {
      int e = tid + 256 * i;
      int co = e >> 3, t4 = e & 7;
      float4 v = *(const float4*)(kb + (size_t)co * HW2 + hwb + t4 * 4);
      *(float4*)(&kt[co * 36 + t4 * 4]) = v;
    }
    // q tile, shifted by (di-2, dj-2), zero-padded
    int hh = h + di - 2;
#pragma unroll
    for (int i = 0; i < 8; ++i) {
      int e = tid + 256 * i;
      int ci = e >> 5, t = e & 31;
      int ww = w0 + t + dj - 2;
      float v = 0.f;
      if (hh >= 0 && hh < 64 && (unsigned)ww < 64u)
        v = qb[(size_t)ci * HW2 + hh * 64 + ww];
      qt[ci * 36 + t] = v;
    }
    __syncthreads();
#pragma unroll
    for (int tq = 0; tq < 8; ++tq) {
      float4 av[4], bv[4];
#pragma unroll
      for (int i = 0; i < 4; ++i)
        av[i] = *(const float4*)(&kt[(ty + 16 * i) * 36 + tq * 4]);
#pragma unroll
      for (int j = 0; j < 4; ++j)
        bv[j] = *(const float4*)(&qt[(tx + 16 * j) * 36 + tq * 4]);
#pragma unroll
      for (int i = 0; i < 4; ++i)
#pragma unroll
        for (int j = 0; j < 4; ++j)
          acc[i][j] += av[i].x * bv[j].x + av[i].y * bv[j].y +
                       av[i].z * bv[j].z + av[i].w * bv[j].w;
    }
    __syncthreads();
  }
#pragma unroll
  for (int i = 0; i < 4; ++i)
#pragma unroll
    for (int j = 0; j < 4; ++j) {
      int co = ty + 16 * i, ci = tx + 16 * j;
      atomicAdd(&attn[(((size_t)b * 25 + sh) * 64 + co) * 64 + ci], acc[i][j]);
    }
}

// ---------------- Kernel 3: ak_t[b,o,co,rs] = valid-conv(attn[b,co], weight[o]) ----
// grid 1024 (b*64+co), block 576 (o = tid/9, rs = tid%9).
__global__ __launch_bounds__(576) void k_akconv(const float* __restrict__ attn,
                                                const float* __restrict__ wgt,
                                                float* __restrict__ akt) {
  int blk = blockIdx.x;
  int b = blk >> 6, co = blk & 63;
  __shared__ float sa[64 * 25];  // [ci][didj]
  int tid = threadIdx.x;
  for (int e = tid; e < 1600; e += 576) {
    int didj = e >> 6, ci = e & 63;
    sa[ci * 25 + didj] = attn[(((size_t)b * 25 + didj) * 64 + co) * 64 + ci];
  }
  __syncthreads();
  int o = tid / 9, rs = tid % 9;
  int ki = rs / 3, kj = rs % 3;
  float acc = 0.f;
  for (int ci = 0; ci < 64; ++ci) {
    const float* wp = wgt + (o * 64 + ci) * 9;
    const float* ap = sa + ci * 25 + ki * 5 + kj;
#pragma unroll
    for (int r = 0; r < 3; ++r)
#pragma unroll
      for (int s = 0; s < 3; ++s) acc += ap[r * 5 + s] * wp[r * 3 + s];
  }
  akt[((size_t)(b * 64 + o) * 64 + co) * 9 + rs] = acc;
}

// ---------------- Kernel 4: per-(b,o) norm + kern assembly ----------------
// grid 1024 (b*64+o), block 576. kern[b,o,i,rs] = w[o,i,rs] + t*akt/max(n,eps)
__global__ __launch_bounds__(576) void k_kern(const float* __restrict__ akt,
                                              const float* __restrict__ wgt,
                                              const float* __restrict__ temp,
                                              float* __restrict__ kern) {
  int blk = blockIdx.x;
  int o = blk & 63;
  int tid = threadIdx.x;
  float v = akt[(size_t)blk * 576 + tid];
  float sq = v * v;
#pragma unroll
  for (int m = 1; m < 64; m <<= 1) sq += __shfl_xor(sq, m, 64);
  __shared__ float wsum[9];
  if ((tid & 63) == 0) wsum[tid >> 6] = sq;
  __syncthreads();
  float tot = 0.f;
#pragma unroll
  for (int i = 0; i < 9; ++i) tot += wsum[i];
  float inv = temp[0] / fmaxf(sqrtf(tot), 1e-12f);
  kern[(size_t)blk * 576 + tid] = wgt[o * 576 + tid] + v * inv;
}

// ---------------- Kernel 5: per-sample 3x3 conv, pad 1, + ReLU -------------
// grid 18432 = b(16) x oc(4) x y2(96) x xt(3), block 256.
// Thread: 2 px x 4 o; kern tile in LDS as [j=ci*9+rs][o16] (pad 20 -> aligned b128).
__global__ __launch_bounds__(256) void k_final(const float* __restrict__ x,
                                               const float* __restrict__ kern,
                                               float* __restrict__ out) {
  int blk = blockIdx.x;
  int xt = blk % 3;
  int t2 = blk / 3;
  int y2 = t2 % 96;
  int t3 = t2 / 96;
  int oc = t3 & 3;
  int b = t3 >> 2;
  int y0 = y2 * 2;
  int obase = oc * 16;

  __shared__ float kl[576 * 20];
  int tid = threadIdx.x;
  for (int e = tid; e < 16 * 576; e += 256) {
    int ol = e / 576, j = e % 576;
    kl[j * 20 + ol] = kern[(size_t)(b * 64 + obase + ol) * 576 + j];
  }
  __syncthreads();

  int pp = tid & 31;
  int yg = (tid >> 5) & 1;
  int og = tid >> 6;  // 0..3
  int px0 = xt * 64 + pp * 2;
  int y = y0 + yg;

  float acc[2][4] = {{0.f, 0.f, 0.f, 0.f}, {0.f, 0.f, 0.f, 0.f}};
  const float* xb = x + (size_t)b * CC_ * HH * WW;
  for (int ci = 0; ci < 64; ++ci) {
    const float* xc = xb + (size_t)ci * (HH * WW);
    float pt[3][4];
#pragma unroll
    for (int r = 0; r < 3; ++r) {
      int yy = y + r - 1;
      bool rok = (unsigned)yy < (unsigned)HH;
#pragma unroll
      for (int c2 = 0; c2 < 4; ++c2) {
        int xx = px0 - 1 + c2;
        bool ok = rok && (unsigned)xx < (unsigned)WW;
        pt[r][c2] = ok ? xc[yy * WW + xx] : 0.f;
      }
    }
#pragma unroll
    for (int r = 0; r < 3; ++r)
#pragma unroll
      for (int s = 0; s < 3; ++s) {
        int j = ci * 9 + r * 3 + s;
        float4 kv = *(const float4*)(&kl[j * 20 + og * 4]);
#pragma unroll
        for (int p = 0; p < 2; ++p) {
          float xv = pt[r][s + p];
          acc[p][0] += xv * kv.x;
          acc[p][1] += xv * kv.y;
          acc[p][2] += xv * kv.z;
          acc[p][3] += xv * kv.w;
        }
      }
  }
#pragma unroll
  for (int c = 0; c < 4; ++c) {
    int o = obase + og * 4 + c;
    size_t ob = ((size_t)(b * 64 + o) * HH + y) * WW + px0;
#pragma unroll
    for (int p = 0; p < 2; ++p) out[ob + p] = fmaxf(acc[p][c], 0.f);
  }
}

extern "C" void kernel_launch(void* const* d_in, const int* in_sizes, int n_in,
                              void* d_out, int out_size, void* d_ws, size_t ws_size,
                              hipStream_t stream) {
  const float* x = (const float*)d_in[0];     // (16,64,192,192)
  const float* wqk = (const float*)d_in[1];   // (128,64,3,3)
  const float* wgt = (const float*)d_in[2];   // (64,64,3,3)
  const float* temp = (const float*)d_in[3];  // (1,1,1)
  float* out = (float*)d_out;                 // (16,64,192,192)
  float* ws = (float*)d_ws;

  float* qk = ws;                  // 16*128*4096      = 8388608 floats
  float* attn = qk + 8388608;      // 16*25*64*64      = 1638400
  float* akt = attn + 1638400;     // 16*64*64*9       = 589824
  float* kern = akt + 589824;      // 16*64*64*9       = 589824
  // total 44.8 MB of workspace

  // attn is accumulated with atomics -> zero it every call (ws is re-poisoned)
  hipMemsetAsync(attn, 0, 1638400 * sizeof(float), stream);

  k_qkconv<<<dim3(BB * H2, 8), 256, 0, stream>>>(x, wqk, qk);
  k_attn<<<dim3(1600), 256, 0, stream>>>(qk, attn);
  k_akconv<<<dim3(1024), 576, 0, stream>>>(attn, wgt, akt);
  k_kern<<<dim3(1024), 576, 0, stream>>>(akt, wgt, temp, kern);
  k_final<<<dim3(18432), 256, 0, stream>>>(x, kern, out);
}

// Round 2
// 1127.805 us; speedup vs baseline: 2.1474x; 2.1474x over previous
//
#include <hip/hip_runtime.h>
#include <cstddef>

#define BB 16
#define CC_ 64
#define HH 192
#define WW 192
#define H2 64
#define W2 64
#define HW2 4096

typedef _Float16 f16x8 __attribute__((ext_vector_type(8)));
typedef float f32x4 __attribute__((ext_vector_type(4)));

// ---------------- Kernel 1: qk = conv3x3 stride3 (VALID) ----------------
__global__ __launch_bounds__(256) void k_qkconv(const float* __restrict__ x,
                                                const float* __restrict__ wqk,
                                                float* __restrict__ qk) {
  const int bx = blockIdx.x;
  const int b = bx >> 6, py = bx & 63;
  const int co_base = blockIdx.y * 16;
  const int tid = threadIdx.x;
  const int px = tid & 63, cg = tid >> 6;

  __shared__ float wl[16 * 768];
  for (int e = tid; e < 16 * 576; e += 256) {
    int cc = e / 576, j = e % 576;
    int ci = j / 9, r9 = j % 9;
    wl[cc * 768 + ci * 12 + r9] = wqk[(size_t)co_base * 576 + e];
  }
  __syncthreads();

  float acc[4] = {0.f, 0.f, 0.f, 0.f};
  const float* xb = x + (size_t)b * CC_ * HH * WW + (3 * py) * WW + 3 * px;
  for (int ci = 0; ci < CC_; ++ci) {
    const float* xp = xb + (size_t)ci * (HH * WW);
    float p[9];
#pragma unroll
    for (int r = 0; r < 3; ++r)
#pragma unroll
      for (int s = 0; s < 3; ++s) p[r * 3 + s] = xp[r * WW + s];
#pragma unroll
    for (int c = 0; c < 4; ++c) {
      const float* w9 = &wl[(cg * 4 + c) * 768 + ci * 12];
      float4 wa = *(const float4*)(w9);
      float4 wb = *(const float4*)(w9 + 4);
      float w8 = w9[8];
      acc[c] += p[0] * wa.x + p[1] * wa.y + p[2] * wa.z + p[3] * wa.w +
                p[4] * wb.x + p[5] * wb.y + p[6] * wb.z + p[7] * wb.w +
                p[8] * w8;
    }
  }
  size_t ob = ((size_t)(b * 128 + co_base + cg * 4) * HW2) + py * 64 + px;
#pragma unroll
  for (int c = 0; c < 4; ++c) qk[ob + (size_t)c * HW2] = acc[c];
}

// ---------------- Kernel 2: attn[b,sh,co,ci] = <k[b,co], q_shift[b,ci]> ----
__global__ __launch_bounds__(256) void k_attn(const float* __restrict__ qk,
                                              float* __restrict__ attn) {
  int blk = blockIdx.x;
  int split = blk & 3;
  int tmp = blk >> 2;
  int sh = tmp % 25;
  int b = tmp / 25;
  int di = sh / 5, dj = sh % 5;
  const float* qb = qk + (size_t)(b * 128) * HW2;
  const float* kb = qb + (size_t)64 * HW2;
  __shared__ float kt[64 * 36];
  __shared__ float qt[64 * 36];
  int tid = threadIdx.x;
  int ty = tid >> 4, tx = tid & 15;
  float acc[4][4];
#pragma unroll
  for (int i = 0; i < 4; ++i)
#pragma unroll
    for (int j = 0; j < 4; ++j) acc[i][j] = 0.f;

  for (int chunk = 0; chunk < 32; ++chunk) {
    int hwb = split * 1024 + chunk * 32;
    int h = hwb >> 6, w0 = hwb & 63;
#pragma unroll
    for (int i = 0; i < 2; ++i) {
      int e = tid + 256 * i;
      int co = e >> 3, t4 = e & 7;
      float4 v = *(const float4*)(kb + (size_t)co * HW2 + hwb + t4 * 4);
      *(float4*)(&kt[co * 36 + t4 * 4]) = v;
    }
    int hh = h + di - 2;
#pragma unroll
    for (int i = 0; i < 8; ++i) {
      int e = tid + 256 * i;
      int ci = e >> 5, t = e & 31;
      int ww = w0 + t + dj - 2;
      float v = 0.f;
      if (hh >= 0 && hh < 64 && (unsigned)ww < 64u)
        v = qb[(size_t)ci * HW2 + hh * 64 + ww];
      qt[ci * 36 + t] = v;
    }
    __syncthreads();
#pragma unroll
    for (int tq = 0; tq < 8; ++tq) {
      float4 av[4], bv[4];
#pragma unroll
      for (int i = 0; i < 4; ++i)
        av[i] = *(const float4*)(&kt[(ty + 16 * i) * 36 + tq * 4]);
#pragma unroll
      for (int j = 0; j < 4; ++j)
        bv[j] = *(const float4*)(&qt[(tx + 16 * j) * 36 + tq * 4]);
#pragma unroll
      for (int i = 0; i < 4; ++i)
#pragma unroll
        for (int j = 0; j < 4; ++j)
          acc[i][j] += av[i].x * bv[j].x + av[i].y * bv[j].y +
                       av[i].z * bv[j].z + av[i].w * bv[j].w;
    }
    __syncthreads();
  }
#pragma unroll
  for (int i = 0; i < 4; ++i)
#pragma unroll
    for (int j = 0; j < 4; ++j) {
      int co = ty + 16 * i, ci = tx + 16 * j;
      atomicAdd(&attn[(((size_t)b * 25 + sh) * 64 + co) * 64 + ci], acc[i][j]);
    }
}

// ---------------- Kernel 3: ak_t[b,o,co,rs] = valid-conv(attn[b,co], weight[o]) ----
__global__ __launch_bounds__(576) void k_akconv(const float* __restrict__ attn,
                                                const float* __restrict__ wgt,
                                                float* __restrict__ akt) {
  int blk = blockIdx.x;
  int b = blk >> 6, co = blk & 63;
  __shared__ float sa[64 * 25];
  int tid = threadIdx.x;
  for (int e = tid; e < 1600; e += 576) {
    int didj = e >> 6, ci = e & 63;
    sa[ci * 25 + didj] = attn[(((size_t)b * 25 + didj) * 64 + co) * 64 + ci];
  }
  __syncthreads();
  int o = tid / 9, rs = tid % 9;
  int ki = rs / 3, kj = rs % 3;
  float acc = 0.f;
  for (int ci = 0; ci < 64; ++ci) {
    const float* wp = wgt + (o * 64 + ci) * 9;
    const float* ap = sa + ci * 25 + ki * 5 + kj;
#pragma unroll
    for (int r = 0; r < 3; ++r)
#pragma unroll
      for (int s = 0; s < 3; ++s) acc += ap[r * 5 + s] * wp[r * 3 + s];
  }
  akt[((size_t)(b * 64 + o) * 64 + co) * 9 + rs] = acc;
}

// ---------------- Kernel 4: per-(b,o) norm + fp16 kern assembly ------------
// writes kern_h[b][rs][o][ci] = (half)(wgt[o,ci,rs] + t*akt/max(n,eps))
__global__ __launch_bounds__(576) void k_kern(const float* __restrict__ akt,
                                              const float* __restrict__ wgt,
                                              const float* __restrict__ temp,
                                              _Float16* __restrict__ kh) {
  int blk = blockIdx.x;
  int b = blk >> 6, o = blk & 63;
  int tid = threadIdx.x;
  float v = akt[(size_t)blk * 576 + tid];
  float sq = v * v;
#pragma unroll
  for (int m = 1; m < 64; m <<= 1) sq += __shfl_xor(sq, m, 64);
  __shared__ float wsum[9];
  if ((tid & 63) == 0) wsum[tid >> 6] = sq;
  __syncthreads();
  float tot = 0.f;
#pragma unroll
  for (int i = 0; i < 9; ++i) tot += wsum[i];
  float inv = temp[0] / fmaxf(sqrtf(tot), 1e-12f);
  float kv = wgt[o * 576 + tid] + v * inv;
  int ci = tid / 9, rs = tid % 9;
  kh[(((size_t)(b * 9 + rs) * 64 + o) * 64) + ci] = (_Float16)kv;
}

// ---------------- Kernel 5: per-sample 3x3 conv via fp16 MFMA implicit GEMM
// grid 2304 = b(16) x yt(48) x xt(3), block 256 (4 waves).
// Block tile: M=64 (all o), N=256 px (4 rows x 64 cols); wave w = row y0+w.
// K = 576 ordered (rs, ci); 18 chunks of 32 (rs, ci-half).
// LDS: x tile fp16 [6 rows][66 cols][ci pad 72] -> B-frag = 1 ds_read_b128.
__global__ __launch_bounds__(256) void k_final(const float* __restrict__ x,
                                               const _Float16* __restrict__ kh,
                                               float* __restrict__ out) {
  int blk = blockIdx.x;
  int xt = blk % 3;
  int t2 = blk / 3;
  int yt = t2 % 48, b = t2 / 48;
  int y0 = yt * 4, x0 = xt * 64;

  __shared__ __align__(16) _Float16 xs[6 * 66 * 72];
  int tid = threadIdx.x;
  const float* xb = x + (size_t)b * (CC_ * HH * WW);

  // stage: tasks (r6, qb, col); 8-ci gather -> one b128 LDS write (zero-filled
  // at image borders). Lanes advance along col -> coalesced global reads.
  for (int it = tid; it < 3168; it += 256) {
    int col = it % 66, t3 = it / 66;
    int qb = t3 & 7, r6 = t3 >> 3;
    int yy = y0 - 1 + r6;
    int xx = x0 - 1 + col;
    bool ok = ((unsigned)yy < (unsigned)HH) && ((unsigned)xx < (unsigned)WW);
    const float* xp = xb + (size_t)(qb * 8) * (HH * WW) + yy * WW + xx;
    f16x8 h;
#pragma unroll
    for (int j = 0; j < 8; ++j)
      h[j] = ok ? (_Float16)xp[(size_t)j * (HH * WW)] : (_Float16)0.f;
    *(f16x8*)&xs[(r6 * 66 + col) * 72 + qb * 8] = h;
  }
  __syncthreads();

  int w = tid >> 6, lane = tid & 63;
  int n16 = lane & 15, quad = lane >> 4;

  f32x4 acc[4][4];
#pragma unroll
  for (int mt = 0; mt < 4; ++mt)
#pragma unroll
    for (int nt = 0; nt < 4; ++nt) acc[mt][nt] = (f32x4){0.f, 0.f, 0.f, 0.f};

  const _Float16* kb = kh + (size_t)b * (9 * 64 * 64);
  for (int ch = 0; ch < 18; ++ch) {
    int rs = ch >> 1, ci0 = (ch & 1) * 32;
    int r = rs / 3, s = rs % 3;
    f16x8 af[4], bf[4];
#pragma unroll
    for (int mt = 0; mt < 4; ++mt)
      af[mt] = *(const f16x8*)(kb + ((size_t)rs * 64 + mt * 16 + n16) * 64 +
                               ci0 + quad * 8);
#pragma unroll
    for (int nt = 0; nt < 4; ++nt)
      bf[nt] = *(const f16x8*)&xs[((w + r) * 66 + nt * 16 + n16 + s) * 72 +
                                  ci0 + quad * 8];
#pragma unroll
    for (int mt = 0; mt < 4; ++mt)
#pragma unroll
      for (int nt = 0; nt < 4; ++nt)
        acc[mt][nt] = __builtin_amdgcn_mfma_f32_16x16x32_f16(
            af[mt], bf[nt], acc[mt][nt], 0, 0, 0);
  }

  int y = y0 + w;
#pragma unroll
  for (int mt = 0; mt < 4; ++mt)
#pragma unroll
    for (int reg = 0; reg < 4; ++reg) {
      int o = mt * 16 + quad * 4 + reg;
      float* op = out + (((size_t)(b * 64 + o) * HH + y) * WW + x0);
#pragma unroll
      for (int nt = 0; nt < 4; ++nt)
        op[nt * 16 + n16] = fmaxf(acc[mt][nt][reg], 0.f);
    }
}

extern "C" void kernel_launch(void* const* d_in, const int* in_sizes, int n_in,
                              void* d_out, int out_size, void* d_ws, size_t ws_size,
                              hipStream_t stream) {
  const float* x = (const float*)d_in[0];     // (16,64,192,192)
  const float* wqk = (const float*)d_in[1];   // (128,64,3,3)
  const float* wgt = (const float*)d_in[2];   // (64,64,3,3)
  const float* temp = (const float*)d_in[3];  // (1,1,1)
  float* out = (float*)d_out;                 // (16,64,192,192)
  float* ws = (float*)d_ws;

  float* qk = ws;                    // 16*128*4096 = 8388608 floats
  float* attn = qk + 8388608;        // 16*25*64*64 = 1638400
  float* akt = attn + 1638400;       // 16*64*64*9  = 589824
  _Float16* kh = (_Float16*)(akt + 589824);  // 16*9*64*64 halfs = 589824 (1.2MB)
  // total ~43.6 MB of workspace

  hipMemsetAsync(attn, 0, 1638400 * sizeof(float), stream);

  k_qkconv<<<dim3(BB * H2, 8), 256, 0, stream>>>(x, wqk, qk);
  k_attn<<<dim3(1600), 256, 0, stream>>>(qk, attn);
  k_akconv<<<dim3(1024), 576, 0, stream>>>(attn, wgt, akt);
  k_kern<<<dim3(1024), 576, 0, stream>>>(akt, wgt, temp, kh);
  k_final<<<dim3(2304), 256, 0, stream>>>(x, kh, out);
}

// Round 3
// 800.870 us; speedup vs baseline: 3.0240x; 1.4082x over previous
//
#include <hip/hip_runtime.h>
#include <cstddef>

#define BB 16
#define CC_ 64
#define HH 192
#define WW 192
#define H2 64
#define W2 64
#define HW2 4096

typedef _Float16 f16x8 __attribute__((ext_vector_type(8)));
typedef float f32x4 __attribute__((ext_vector_type(4)));

// ---------------- Kernel 0: pack wqk fp32 -> fp16 A-fragment layout --------
// wh[kc=(r*2+cihalf)][co 128][s*32 + ci%32], kc in 0..5
__global__ __launch_bounds__(1024) void k_wpack(const float* __restrict__ wqk,
                                                _Float16* __restrict__ wh) {
  int e = blockIdx.x * 1024 + threadIdx.x;  // 72*1024 = 73728 = 128*576
  int co = e / 576, t = e % 576;
  int ci = t / 9, rs = t % 9;
  int r = rs / 3, s = rs % 3;
  int ch = ci >> 5, t32 = ci & 31;
  wh[(((r * 2 + ch) * 128 + co) * 96) + s * 32 + t32] = (_Float16)wqk[e];
}

// ---------------- Kernel 1: qk conv3x3 stride3 via fp16 MFMA implicit GEMM -
// grid 512 = b(16) x pt(32); block 256 (4 waves). Block tile: M=128 co,
// N=128 px (2 py-rows x 64). Wave: co-half x one py-row (4x4 16x16 tiles).
// K = 576 as 6 chunks (r, ci-half): stage x slab [row2][col192][ci32 pad36].
// Stride-3 conv => patches non-overlapping => x read exactly once.
__global__ __launch_bounds__(256) void k_qkconv(const float* __restrict__ x,
                                                const _Float16* __restrict__ wh,
                                                _Float16* __restrict__ qkh) {
  int blk = blockIdx.x;
  int pt = blk & 31, b = blk >> 5;
  __shared__ __align__(16) _Float16 xs[2 * 192 * 36];
  int tid = threadIdx.x;
  const float* xb = x + (size_t)b * (CC_ * HH * WW);
  int w = tid >> 6, lane = tid & 63, n16 = lane & 15, quad = lane >> 4;
  int mh = w & 1, nh = w >> 1;

  f32x4 acc[4][4];
#pragma unroll
  for (int mt = 0; mt < 4; ++mt)
#pragma unroll
    for (int nt = 0; nt < 4; ++nt) acc[mt][nt] = (f32x4){0.f, 0.f, 0.f, 0.f};

  for (int kc = 0; kc < 6; ++kc) {
    int r = kc >> 1, ch = kc & 1;
    __syncthreads();
    // stage: 1536 tasks = (row2 x qb4) x col192; 8-ci gather -> b128 write
    for (int i = 0; i < 6; ++i) {
      int it = tid + 256 * i;
      int col = it % 192, t3 = it / 192;
      int row = t3 >> 2, qb = t3 & 3;
      int irow = 6 * pt + 3 * row + r;
      const float* xp = xb + (size_t)(ch * 32 + qb * 8) * (HH * WW) + irow * WW + col;
      f16x8 h;
#pragma unroll
      for (int j = 0; j < 8; ++j) h[j] = (_Float16)xp[(size_t)j * (HH * WW)];
      *(f16x8*)&xs[(row * 192 + col) * 36 + qb * 8] = h;
    }
    __syncthreads();
    const _Float16* wp = wh + (size_t)kc * (128 * 96);
#pragma unroll
    for (int s = 0; s < 3; ++s) {
      f16x8 af[4], bf[4];
#pragma unroll
      for (int mt = 0; mt < 4; ++mt)
        af[mt] = *(const f16x8*)(wp + (mh * 64 + mt * 16 + n16) * 96 + s * 32 + quad * 8);
#pragma unroll
      for (int nt = 0; nt < 4; ++nt)
        bf[nt] = *(const f16x8*)&xs[(nh * 192 + 3 * (nt * 16 + n16) + s) * 36 + quad * 8];
#pragma unroll
      for (int mt = 0; mt < 4; ++mt)
#pragma unroll
        for (int nt = 0; nt < 4; ++nt)
          acc[mt][nt] = __builtin_amdgcn_mfma_f32_16x16x32_f16(af[mt], bf[nt],
                                                               acc[mt][nt], 0, 0, 0);
    }
  }
  int py = pt * 2 + nh;
#pragma unroll
  for (int mt = 0; mt < 4; ++mt)
#pragma unroll
    for (int reg = 0; reg < 4; ++reg) {
      int co = mh * 64 + mt * 16 + quad * 4 + reg;
      _Float16* op = qkh + (size_t)(b * 128 + co) * HW2 + py * 64;
#pragma unroll
      for (int nt = 0; nt < 4; ++nt) op[nt * 16 + n16] = (_Float16)acc[mt][nt][reg];
    }
}

// ---------------- Kernel 2: attn via fp16 MFMA ----------------
// grid 800 = (b*25+sh)*2 + sp; block 256. Each wave: full 64x64 (co x ci)
// for its K-quarter; 8 chunks of 256 p (4 rows). LDS-atomic reduce, write
// split part sp (no global atomics, no memset).
__global__ __launch_bounds__(256) void k_attn(const _Float16* __restrict__ qkh,
                                              float* __restrict__ attn_p) {
  int blk = blockIdx.x;
  int sp = blk & 1;
  int t = blk >> 1;
  int sh = t % 25, b = t / 25;
  int di = sh / 5 - 2, dj = sh % 5 - 2;
  const _Float16* qb = qkh + (size_t)b * 128 * HW2;
  const _Float16* kb = qb + (size_t)64 * HW2;
  __shared__ __align__(16) _Float16 ks[64 * 264];
  __shared__ __align__(16) _Float16 qs[64 * 264];
  int tid = threadIdx.x, w = tid >> 6, lane = tid & 63;
  int n16 = lane & 15, quad = lane >> 4;

  f32x4 acc[4][4];
#pragma unroll
  for (int mt = 0; mt < 4; ++mt)
#pragma unroll
    for (int nt = 0; nt < 4; ++nt) acc[mt][nt] = (f32x4){0.f, 0.f, 0.f, 0.f};

  for (int c = 0; c < 8; ++c) {
    int R0 = sp * 32 + c * 4;
    __syncthreads();
    // k tile: straight b128 copy, [co][264]
    for (int i = 0; i < 8; ++i) {
      int it = tid + 256 * i;
      int g = it & 31, co = it >> 5;
      f16x8 v = *(const f16x8*)(kb + (size_t)co * HW2 + R0 * 64 + g * 8);
      *(f16x8*)&ks[co * 264 + g * 8] = v;
    }
    // q tile: (di,dj)-shifted, zero-padded, element u16 gather
    for (int i = 0; i < 8; ++i) {
      int it = tid + 256 * i;
      int grp = it & 7, row = (it >> 3) & 3, ci = it >> 5;
      int rr = R0 + row + di;
      f16x8 v;
      if ((unsigned)rr < 64u) {
        const _Float16* qp = qb + (size_t)ci * HW2 + rr * 64;
#pragma unroll
        for (int j = 0; j < 8; ++j) {
          int cc = grp * 8 + j + dj;
          v[j] = ((unsigned)cc < 64u) ? qp[cc] : (_Float16)0.f;
        }
      } else {
#pragma unroll
        for (int j = 0; j < 8; ++j) v[j] = (_Float16)0.f;
      }
      *(f16x8*)&qs[ci * 264 + row * 64 + grp * 8] = v;
    }
    __syncthreads();
    // wave w: K-instr w*2, w*2+1 of this chunk
#pragma unroll
    for (int ki = 0; ki < 2; ++ki) {
      int ko = (w * 2 + ki) * 32 + quad * 8;
      f16x8 af[4], bf[4];
#pragma unroll
      for (int mt = 0; mt < 4; ++mt)
        af[mt] = *(const f16x8*)&ks[(mt * 16 + n16) * 264 + ko];
#pragma unroll
      for (int nt = 0; nt < 4; ++nt)
        bf[nt] = *(const f16x8*)&qs[(nt * 16 + n16) * 264 + ko];
#pragma unroll
      for (int mt = 0; mt < 4; ++mt)
#pragma unroll
        for (int nt = 0; nt < 4; ++nt)
          acc[mt][nt] = __builtin_amdgcn_mfma_f32_16x16x32_f16(af[mt], bf[nt],
                                                               acc[mt][nt], 0, 0, 0);
    }
  }
  // cross-wave reduction in LDS (reuse ks region), pad 66 -> 2-way (free)
  float* racc = (float*)ks;
  __syncthreads();
  for (int e = tid; e < 64 * 66; e += 256) racc[e] = 0.f;
  __syncthreads();
#pragma unroll
  for (int mt = 0; mt < 4; ++mt) {
    int co = mt * 16 + quad * 4;
#pragma unroll
    for (int reg = 0; reg < 4; ++reg)
#pragma unroll
      for (int nt = 0; nt < 4; ++nt)
        atomicAdd(&racc[(co + reg) * 66 + nt * 16 + n16], acc[mt][nt][reg]);
  }
  __syncthreads();
  float* op = attn_p + ((size_t)sp * 400 + b * 25 + sh) * 4096;
  for (int e = tid; e < 4096; e += 256)
    op[e] = racc[(e >> 6) * 66 + (e & 63)];
}

// ---------------- Kernel 3: ak_t = valid-conv(attn, weight), sums 2 parts --
__global__ __launch_bounds__(576) void k_akconv(const float* __restrict__ attn_p,
                                                const float* __restrict__ wgt,
                                                float* __restrict__ akt) {
  int blk = blockIdx.x;
  int b = blk >> 6, co = blk & 63;
  __shared__ float sa[64 * 25];
  int tid = threadIdx.x;
  for (int e = tid; e < 1600; e += 576) {
    int didj = e >> 6, ci = e & 63;
    size_t idx = (((size_t)b * 25 + didj) * 64 + co) * 64 + ci;
    sa[ci * 25 + didj] = attn_p[idx] + attn_p[(size_t)400 * 4096 + idx];
  }
  __syncthreads();
  int o = tid / 9, rs = tid % 9;
  int ki = rs / 3, kj = rs % 3;
  float acc = 0.f;
  for (int ci = 0; ci < 64; ++ci) {
    const float* wp = wgt + (o * 64 + ci) * 9;
    const float* ap = sa + ci * 25 + ki * 5 + kj;
#pragma unroll
    for (int r = 0; r < 3; ++r)
#pragma unroll
      for (int s = 0; s < 3; ++s) acc += ap[r * 5 + s] * wp[r * 3 + s];
  }
  akt[((size_t)(b * 64 + o) * 64 + co) * 9 + rs] = acc;
}

// ---------------- Kernel 4: per-(b,o) norm + fp16 kern assembly ------------
__global__ __launch_bounds__(576) void k_kern(const float* __restrict__ akt,
                                              const float* __restrict__ wgt,
                                              const float* __restrict__ temp,
                                              _Float16* __restrict__ kh) {
  int blk = blockIdx.x;
  int b = blk >> 6, o = blk & 63;
  int tid = threadIdx.x;
  float v = akt[(size_t)blk * 576 + tid];
  float sq = v * v;
#pragma unroll
  for (int m = 1; m < 64; m <<= 1) sq += __shfl_xor(sq, m, 64);
  __shared__ float wsum[9];
  if ((tid & 63) == 0) wsum[tid >> 6] = sq;
  __syncthreads();
  float tot = 0.f;
#pragma unroll
  for (int i = 0; i < 9; ++i) tot += wsum[i];
  float inv = temp[0] / fmaxf(sqrtf(tot), 1e-12f);
  float kv = wgt[o * 576 + tid] + v * inv;
  int ci = tid / 9, rs = tid % 9;
  kh[(((size_t)(b * 9 + rs) * 64 + o) * 64) + ci] = (_Float16)kv;
}

// ---------------- Kernel 5: per-sample 3x3 conv via fp16 MFMA --------------
__global__ __launch_bounds__(256) void k_final(const float* __restrict__ x,
                                               const _Float16* __restrict__ kh,
                                               float* __restrict__ out) {
  int blk = blockIdx.x;
  int xt = blk % 3;
  int t2 = blk / 3;
  int yt = t2 % 48, b = t2 / 48;
  int y0 = yt * 4, x0 = xt * 64;

  __shared__ __align__(16) _Float16 xs[6 * 66 * 72];
  int tid = threadIdx.x;
  const float* xb = x + (size_t)b * (CC_ * HH * WW);

  for (int it = tid; it < 3168; it += 256) {
    int col = it % 66, t3 = it / 66;
    int qb = t3 & 7, r6 = t3 >> 3;
    int yy = y0 - 1 + r6;
    int xx = x0 - 1 + col;
    bool ok = ((unsigned)yy < (unsigned)HH) && ((unsigned)xx < (unsigned)WW);
    const float* xp = xb + (size_t)(qb * 8) * (HH * WW) + yy * WW + xx;
    f16x8 h;
#pragma unroll
    for (int j = 0; j < 8; ++j)
      h[j] = ok ? (_Float16)xp[(size_t)j * (HH * WW)] : (_Float16)0.f;
    *(f16x8*)&xs[(r6 * 66 + col) * 72 + qb * 8] = h;
  }
  __syncthreads();

  int w = tid >> 6, lane = tid & 63;
  int n16 = lane & 15, quad = lane >> 4;

  f32x4 acc[4][4];
#pragma unroll
  for (int mt = 0; mt < 4; ++mt)
#pragma unroll
    for (int nt = 0; nt < 4; ++nt) acc[mt][nt] = (f32x4){0.f, 0.f, 0.f, 0.f};

  const _Float16* kb = kh + (size_t)b * (9 * 64 * 64);
  for (int ch = 0; ch < 18; ++ch) {
    int rs = ch >> 1, ci0 = (ch & 1) * 32;
    int r = rs / 3, s = rs % 3;
    f16x8 af[4], bf[4];
#pragma unroll
    for (int mt = 0; mt < 4; ++mt)
      af[mt] = *(const f16x8*)(kb + ((size_t)rs * 64 + mt * 16 + n16) * 64 +
                               ci0 + quad * 8);
#pragma unroll
    for (int nt = 0; nt < 4; ++nt)
      bf[nt] = *(const f16x8*)&xs[((w + r) * 66 + nt * 16 + n16 + s) * 72 +
                                  ci0 + quad * 8];
#pragma unroll
    for (int mt = 0; mt < 4; ++mt)
#pragma unroll
      for (int nt = 0; nt < 4; ++nt)
        acc[mt][nt] = __builtin_amdgcn_mfma_f32_16x16x32_f16(
            af[mt], bf[nt], acc[mt][nt], 0, 0, 0);
  }

  int y = y0 + w;
#pragma unroll
  for (int mt = 0; mt < 4; ++mt)
#pragma unroll
    for (int reg = 0; reg < 4; ++reg) {
      int o = mt * 16 + quad * 4 + reg;
      float* op = out + (((size_t)(b * 64 + o) * HH + y) * WW + x0);
#pragma unroll
      for (int nt = 0; nt < 4; ++nt)
        op[nt * 16 + n16] = fmaxf(acc[mt][nt][reg], 0.f);
    }
}

extern "C" void kernel_launch(void* const* d_in, const int* in_sizes, int n_in,
                              void* d_out, int out_size, void* d_ws, size_t ws_size,
                              hipStream_t stream) {
  const float* x = (const float*)d_in[0];     // (16,64,192,192)
  const float* wqk = (const float*)d_in[1];   // (128,64,3,3)
  const float* wgt = (const float*)d_in[2];   // (64,64,3,3)
  const float* temp = (const float*)d_in[3];  // (1,1,1)
  float* out = (float*)d_out;
  char* ws = (char*)d_ws;

  _Float16* qkh = (_Float16*)ws;                      // 16*128*4096 h = 16.78 MB
  float* attn_p = (float*)(ws + 16777216);            // 2*400*4096 f  = 13.11 MB
  float* akt = (float*)(ws + 16777216 + 13107200);    // 589824 f      =  2.36 MB
  _Float16* kh = (_Float16*)(ws + 16777216 + 13107200 + 2359296);  // 1.18 MB
  _Float16* wh = (_Float16*)(ws + 16777216 + 13107200 + 2359296 + 1179648);  // 147 KB
  // total ~33.6 MB

  k_wpack<<<dim3(72), 1024, 0, stream>>>(wqk, wh);
  k_qkconv<<<dim3(512), 256, 0, stream>>>(x, wh, qkh);
  k_attn<<<dim3(800), 256, 0, stream>>>(qkh, attn_p);
  k_akconv<<<dim3(1024), 576, 0, stream>>>(attn_p, wgt, akt);
  k_kern<<<dim3(1024), 576, 0, stream>>>(akt, wgt, temp, kh);
  k_final<<<dim3(2304), 256, 0, stream>>>(x, kh, out);
}

// Round 4
// 660.919 us; speedup vs baseline: 3.6644x; 1.2118x over previous
//
#include <hip/hip_runtime.h>
#include <cstddef>

#define BB 16
#define CC_ 64
#define HH 192
#define WW 192
#define HW2 4096

typedef _Float16 f16x8 __attribute__((ext_vector_type(8)));
typedef float f32x4 __attribute__((ext_vector_type(4)));

// ---------------- Kernel W: pack wqk fp32 -> fp16 A-fragment layout --------
// wh[kc=(r*2+cihalf)][co 128][s*32 + ci%32]
__global__ __launch_bounds__(1024) void k_wpack(const float* __restrict__ wqk,
                                                _Float16* __restrict__ wh) {
  int e = blockIdx.x * 1024 + threadIdx.x;  // 72*1024 = 73728 = 128*576
  int co = e / 576, t = e % 576;
  int ci = t / 9, rs = t % 9;
  int r = rs / 3, s = rs % 3;
  int ch = ci >> 5, t32 = ci & 31;
  wh[(((r * 2 + ch) * 128 + co) * 96) + s * 32 + t32] = (_Float16)wqk[e];
}

// ---------------- Kernel X: x fp32 NCHW -> fp16 channels-last xh[b][y][x][ci]
// grid 16*192*3, block 256. LDS transpose tile 64ci x 64col.
__global__ __launch_bounds__(256) void k_xpack(const float* __restrict__ x,
                                               _Float16* __restrict__ xh) {
  int blk = blockIdx.x;
  int xg = blk % 3;
  int t = blk / 3;
  int y = t % 192, b = t / 192;
  int x0 = xg * 64;
  __shared__ _Float16 tl[64 * 72];  // [col][ci]
  int tid = threadIdx.x;
  int ci = tid >> 2, c4 = (tid & 3) * 16;
  const float* xp = x + ((size_t)(b * 64 + ci) * HH + y) * WW + x0 + c4;
#pragma unroll
  for (int i = 0; i < 4; ++i) {
    float4 v = *(const float4*)(xp + i * 4);
    tl[(c4 + i * 4 + 0) * 72 + ci] = (_Float16)v.x;
    tl[(c4 + i * 4 + 1) * 72 + ci] = (_Float16)v.y;
    tl[(c4 + i * 4 + 2) * 72 + ci] = (_Float16)v.z;
    tl[(c4 + i * 4 + 3) * 72 + ci] = (_Float16)v.w;
  }
  __syncthreads();
#pragma unroll
  for (int i = 0; i < 2; ++i) {
    int e = tid + 256 * i;
    int col = e >> 3, g = e & 7;
    *(f16x8*)(xh + (((size_t)b * HH + y) * WW + x0 + col) * 64 + g * 8) =
        *(f16x8*)&tl[col * 72 + g * 8];
  }
}

// ---------------- Kernel 1: qk conv3x3 stride3, no-LDS MFMA implicit GEMM --
// grid 512 = b x pt(32); block 256. M=128 co, N=128 px (2 rows x 64).
// Stride-3 => x read exactly once; B-frags straight from xh (16B aligned).
__global__ __launch_bounds__(256) void k_qkconv(const _Float16* __restrict__ xh,
                                                const _Float16* __restrict__ wh,
                                                _Float16* __restrict__ qkh) {
  int blk = blockIdx.x;
  int pt = blk & 31, b = blk >> 5;
  int tid = threadIdx.x;
  int w = tid >> 6, lane = tid & 63, n16 = lane & 15, quad = lane >> 4;
  int mh = w & 1, nh = w >> 1;
  const _Float16* xb = xh + (size_t)b * (HH * WW * 64);

  f32x4 acc[4][4];
#pragma unroll
  for (int mt = 0; mt < 4; ++mt)
#pragma unroll
    for (int nt = 0; nt < 4; ++nt) acc[mt][nt] = (f32x4){0.f, 0.f, 0.f, 0.f};

#pragma unroll
  for (int kc = 0; kc < 6; ++kc) {
    int r = kc >> 1, ch = kc & 1;
    int irow = 6 * pt + 3 * nh + r;
    const _Float16* wp = wh + (size_t)kc * (128 * 96);
#pragma unroll
    for (int s = 0; s < 3; ++s) {
      f16x8 af[4], bf[4];
#pragma unroll
      for (int mt = 0; mt < 4; ++mt)
        af[mt] = *(const f16x8*)(wp + (mh * 64 + mt * 16 + n16) * 96 + s * 32 +
                                 quad * 8);
#pragma unroll
      for (int nt = 0; nt < 4; ++nt) {
        int col = 3 * (nt * 16 + n16) + s;
        bf[nt] = *(const f16x8*)(xb + ((size_t)irow * WW + col) * 64 + ch * 32 +
                                 quad * 8);
      }
#pragma unroll
      for (int mt = 0; mt < 4; ++mt)
#pragma unroll
        for (int nt = 0; nt < 4; ++nt)
          acc[mt][nt] = __builtin_amdgcn_mfma_f32_16x16x32_f16(af[mt], bf[nt],
                                                               acc[mt][nt], 0, 0, 0);
    }
  }
  int py = pt * 2 + nh;
#pragma unroll
  for (int mt = 0; mt < 4; ++mt)
#pragma unroll
    for (int reg = 0; reg < 4; ++reg) {
      int co = mh * 64 + mt * 16 + quad * 4 + reg;
      _Float16* op = qkh + (size_t)(b * 128 + co) * HW2 + py * 64;
#pragma unroll
      for (int nt = 0; nt < 4; ++nt) op[nt * 16 + n16] = (_Float16)acc[mt][nt][reg];
    }
}

// ---------------- Kernel Q: build padded shifted q copies ------------------
// qpad[b][djx][ci][68][64]: row-pad 2, col pre-shifted by dj=djx-2, zero-fill.
__global__ __launch_bounds__(256) void k_qpad(const _Float16* __restrict__ qkh,
                                              _Float16* __restrict__ qpad) {
  int blk = blockIdx.x;  // 1024 = b*64+ci
  int b = blk >> 6, ci = blk & 63;
  __shared__ _Float16 qrow[4096];
  int tid = threadIdx.x;
  const _Float16* src = qkh + (size_t)(b * 128 + ci) * HW2;
#pragma unroll
  for (int i = 0; i < 2; ++i)
    ((f16x8*)qrow)[tid + 256 * i] = ((const f16x8*)src)[tid + 256 * i];
  __syncthreads();
  _Float16* dst = qpad + ((size_t)(b * 5) * 64 + ci) * 4352;
  for (int it = tid; it < 2720; it += 256) {
    int w8 = it & 7;
    int hr = (it >> 3) % 68;
    int djx = (it >> 3) / 68;
    int h = hr - 2;
    f16x8 v = (f16x8)(_Float16)0;
    if ((unsigned)h < 64u) {
#pragma unroll
      for (int j = 0; j < 8; ++j) {
        int c = w8 * 8 + j + djx - 2;
        if ((unsigned)c < 64u) v[j] = qrow[h * 64 + c];
      }
    }
    *(f16x8*)(dst + (size_t)djx * (64 * 4352) + hr * 64 + w8 * 8) = v;
  }
}

// ---------------- Kernel 2: attn via MFMA, branch-free aligned staging -----
// grid 800 = ((b*25+sh)<<1)|sp; block 256. 64x64 co x ci; K=2048 per part.
__global__ __launch_bounds__(256) void k_attn(const _Float16* __restrict__ qkh,
                                              const _Float16* __restrict__ qpad,
                                              float* __restrict__ attn_p) {
  int blk = blockIdx.x;
  int sp = blk & 1;
  int t = blk >> 1;
  int sh = t % 25, b = t / 25;
  int djx = sh % 5, dix = sh / 5;
  const _Float16* kb = qkh + (size_t)(b * 128 + 64) * HW2;
  const _Float16* qpb = qpad + ((size_t)(b * 5 + djx) * 64) * 4352 + dix * 64;
  __shared__ __align__(16) _Float16 ks[64 * 264];
  __shared__ __align__(16) _Float16 qs[64 * 264];
  int tid = threadIdx.x, w = tid >> 6, lane = tid & 63;
  int n16 = lane & 15, quad = lane >> 4;

  f32x4 acc[4][4];
#pragma unroll
  for (int mt = 0; mt < 4; ++mt)
#pragma unroll
    for (int nt = 0; nt < 4; ++nt) acc[mt][nt] = (f32x4){0.f, 0.f, 0.f, 0.f};

  for (int c = 0; c < 8; ++c) {
    int p0 = sp * 2048 + c * 256;
    __syncthreads();
#pragma unroll
    for (int i = 0; i < 8; ++i) {
      int e = tid + 256 * i;
      int g = e & 31, row = e >> 5;
      *(f16x8*)&ks[row * 264 + g * 8] =
          *(const f16x8*)(kb + (size_t)row * HW2 + p0 + g * 8);
      *(f16x8*)&qs[row * 264 + g * 8] =
          *(const f16x8*)(qpb + (size_t)row * 4352 + p0 + g * 8);
    }
    __syncthreads();
#pragma unroll
    for (int ki = 0; ki < 2; ++ki) {
      int ko = (w * 2 + ki) * 32 + quad * 8;
      f16x8 af[4], bf[4];
#pragma unroll
      for (int mt = 0; mt < 4; ++mt)
        af[mt] = *(const f16x8*)&ks[(mt * 16 + n16) * 264 + ko];
#pragma unroll
      for (int nt = 0; nt < 4; ++nt)
        bf[nt] = *(const f16x8*)&qs[(nt * 16 + n16) * 264 + ko];
#pragma unroll
      for (int mt = 0; mt < 4; ++mt)
#pragma unroll
        for (int nt = 0; nt < 4; ++nt)
          acc[mt][nt] = __builtin_amdgcn_mfma_f32_16x16x32_f16(af[mt], bf[nt],
                                                               acc[mt][nt], 0, 0, 0);
    }
  }
  float* racc = (float*)ks;
  __syncthreads();
  for (int e = tid; e < 64 * 66; e += 256) racc[e] = 0.f;
  __syncthreads();
#pragma unroll
  for (int mt = 0; mt < 4; ++mt) {
    int co = mt * 16 + quad * 4;
#pragma unroll
    for (int reg = 0; reg < 4; ++reg)
#pragma unroll
      for (int nt = 0; nt < 4; ++nt)
        atomicAdd(&racc[(co + reg) * 66 + nt * 16 + n16], acc[mt][nt][reg]);
  }
  __syncthreads();
  float* op = attn_p + ((size_t)sp * 400 + b * 25 + sh) * 4096;
  for (int e = tid; e < 4096; e += 256) op[e] = racc[(e >> 6) * 66 + (e & 63)];
}

// ---------------- Kernel 3: ak_t = valid-conv(attn, weight), sums 2 parts --
__global__ __launch_bounds__(576) void k_akconv(const float* __restrict__ attn_p,
                                                const float* __restrict__ wgt,
                                                float* __restrict__ akt) {
  int blk = blockIdx.x;
  int b = blk >> 6, co = blk & 63;
  __shared__ float sa[64 * 25];
  int tid = threadIdx.x;
  for (int e = tid; e < 1600; e += 576) {
    int didj = e >> 6, ci = e & 63;
    size_t idx = (((size_t)b * 25 + didj) * 64 + co) * 64 + ci;
    sa[ci * 25 + didj] = attn_p[idx] + attn_p[(size_t)400 * 4096 + idx];
  }
  __syncthreads();
  int o = tid / 9, rs = tid % 9;
  int ki = rs / 3, kj = rs % 3;
  float acc = 0.f;
  for (int ci = 0; ci < 64; ++ci) {
    const float* wp = wgt + (o * 64 + ci) * 9;
    const float* ap = sa + ci * 25 + ki * 5 + kj;
#pragma unroll
    for (int r = 0; r < 3; ++r)
#pragma unroll
      for (int s = 0; s < 3; ++s) acc += ap[r * 5 + s] * wp[r * 3 + s];
  }
  akt[((size_t)(b * 64 + o) * 64 + co) * 9 + rs] = acc;
}

// ---------------- Kernel 4: per-(b,o) norm + fp16 kern assembly ------------
__global__ __launch_bounds__(576) void k_kern(const float* __restrict__ akt,
                                              const float* __restrict__ wgt,
                                              const float* __restrict__ temp,
                                              _Float16* __restrict__ kh) {
  int blk = blockIdx.x;
  int o = blk & 63;
  int tid = threadIdx.x;
  float v = akt[(size_t)blk * 576 + tid];
  float sq = v * v;
#pragma unroll
  for (int m = 1; m < 64; m <<= 1) sq += __shfl_xor(sq, m, 64);
  __shared__ float wsum[9];
  if ((tid & 63) == 0) wsum[tid >> 6] = sq;
  __syncthreads();
  float tot = 0.f;
#pragma unroll
  for (int i = 0; i < 9; ++i) tot += wsum[i];
  float inv = temp[0] / fmaxf(sqrtf(tot), 1e-12f);
  float kv = wgt[o * 576 + tid] + v * inv;
  int b = blk >> 6;
  int ci = tid / 9, rs = tid % 9;
  kh[(((size_t)(b * 9 + rs) * 64 + o) * 64) + ci] = (_Float16)kv;
}

// ---------------- Kernel 5: dynamic 3x3 conv + ReLU, no-LDS MFMA -----------
// grid 2304 = b x yt(48) x xt(3); block 256 (4 waves, wave = one y-row).
// B-frags straight from xh (predicated at borders); A-frags from kh (L2-hot).
__global__ __launch_bounds__(256) void k_final(const _Float16* __restrict__ xh,
                                               const _Float16* __restrict__ kh,
                                               float* __restrict__ out) {
  int blk = blockIdx.x;
  int xt = blk % 3;
  int t2 = blk / 3;
  int yt = t2 % 48, b = t2 / 48;
  int y0 = yt * 4, x0 = xt * 64;

  int tid = threadIdx.x;
  int w = tid >> 6, lane = tid & 63;
  int n16 = lane & 15, quad = lane >> 4;
  int y = y0 + w;

  const _Float16* xb = xh + (size_t)b * (HH * WW * 64);
  const _Float16* kb = kh + (size_t)b * (9 * 64 * 64);

  f32x4 acc[4][4];
#pragma unroll
  for (int mt = 0; mt < 4; ++mt)
#pragma unroll
    for (int nt = 0; nt < 4; ++nt) acc[mt][nt] = (f32x4){0.f, 0.f, 0.f, 0.f};

#pragma unroll
  for (int ch = 0; ch < 18; ++ch) {
    int rs = ch >> 1, ci0 = (ch & 1) * 32;
    int r = rs / 3, s = rs % 3;
    int rr = y + r - 1;
    f16x8 af[4], bf[4];
#pragma unroll
    for (int mt = 0; mt < 4; ++mt)
      af[mt] = *(const f16x8*)(kb + ((size_t)rs * 64 + mt * 16 + n16) * 64 +
                               ci0 + quad * 8);
    bool rok = (unsigned)rr < (unsigned)HH;
#pragma unroll
    for (int nt = 0; nt < 4; ++nt) {
      int xx = x0 + nt * 16 + n16 + s - 1;
      bool ok = rok && ((unsigned)xx < (unsigned)WW);
      bf[nt] = ok ? *(const f16x8*)(xb + ((size_t)rr * WW + xx) * 64 + ci0 +
                                    quad * 8)
                  : (f16x8)(_Float16)0;
    }
#pragma unroll
    for (int mt = 0; mt < 4; ++mt)
#pragma unroll
      for (int nt = 0; nt < 4; ++nt)
        acc[mt][nt] = __builtin_amdgcn_mfma_f32_16x16x32_f16(af[mt], bf[nt],
                                                             acc[mt][nt], 0, 0, 0);
  }

#pragma unroll
  for (int mt = 0; mt < 4; ++mt)
#pragma unroll
    for (int reg = 0; reg < 4; ++reg) {
      int o = mt * 16 + quad * 4 + reg;
      float* op = out + (((size_t)(b * 64 + o) * HH + y) * WW + x0);
#pragma unroll
      for (int nt = 0; nt < 4; ++nt)
        op[nt * 16 + n16] = fmaxf(acc[mt][nt][reg], 0.f);
    }
}

extern "C" void kernel_launch(void* const* d_in, const int* in_sizes, int n_in,
                              void* d_out, int out_size, void* d_ws, size_t ws_size,
                              hipStream_t stream) {
  const float* x = (const float*)d_in[0];     // (16,64,192,192)
  const float* wqk = (const float*)d_in[1];   // (128,64,3,3)
  const float* wgt = (const float*)d_in[2];   // (64,64,3,3)
  const float* temp = (const float*)d_in[3];  // (1,1,1)
  float* out = (float*)d_out;
  char* ws = (char*)d_ws;

  // Workspace layout (bytes):
  _Float16* xh = (_Float16*)ws;                          // 75,497,472
  _Float16* qkh = (_Float16*)(ws + 75497472);            // 16,777,216
  _Float16* qpad = (_Float16*)(ws + 92274688);           // 44,564,480
  float* attn_p = (float*)(ws + 136839168);              // 13,107,200
  _Float16* wh = (_Float16*)(ws + 149946368);            //    147,456
  // akt/kh alias the qpad region (qpad dead after k_attn):
  float* akt = (float*)(ws + 92274688);                  //  2,359,296
  _Float16* kh = (_Float16*)(ws + 92274688 + 2359296);   //  1,179,648
  // total ~150.1 MB

  k_wpack<<<dim3(72), 1024, 0, stream>>>(wqk, wh);
  k_xpack<<<dim3(9216), 256, 0, stream>>>(x, xh);
  k_qkconv<<<dim3(512), 256, 0, stream>>>(xh, wh, qkh);
  k_qpad<<<dim3(1024), 256, 0, stream>>>(qkh, qpad);
  k_attn<<<dim3(800), 256, 0, stream>>>(qkh, qpad, attn_p);
  k_akconv<<<dim3(1024), 576, 0, stream>>>(attn_p, wgt, akt);
  k_kern<<<dim3(1024), 576, 0, stream>>>(akt, wgt, temp, kh);
  k_final<<<dim3(2304), 256, 0, stream>>>(xh, kh, out);
}